// Round 1
// baseline (1608.358 us; speedup 1.0000x reference)
//
#include <hip/hip_runtime.h>

#define BATCH 16
#define CIN   32
#define HH    128
#define WW    128
#define BO    32
#define OCH   128   // 4*BO
#define NCH   16    // h-chunks
#define RPC   8     // rows per chunk

// ws layout: [0,1024): flags (int, BATCH*NCH used, memset to 0 each launch)
//            [1024, 1024 + BATCH*NCH*WW*BO*4): boundary handoff buffer (fp32)

__global__ __launch_bounds__(256) void diag_lstm_scan(
    const float* __restrict__ x, const float* __restrict__ W2g,
    const float* __restrict__ b2, const float* __restrict__ W1g,
    const float* __restrict__ b1, float* __restrict__ out,
    int* __restrict__ flags, float* __restrict__ hand)
{
    const int tid = threadIdx.x;
    const int blk = blockIdx.x;
    const int b = blk / NCH;
    const int k = blk % NCH;
    const int h0 = k * RPC;

    __shared__ float phs[RPC + 1][BO];   // phs[0] = boundary row (prev chunk, prev step)
    __shared__ float xbuf[RPC][CIN];
    __shared__ float gbuf[RPC][OCH];

    // zero-init state
    for (int i = tid; i < (RPC + 1) * BO; i += 256) ((float*)phs)[i] = 0.f;

    // matmul role: o = output channel, half = which 4 rows
    const int o    = tid & (OCH - 1);
    const int half = tid >> 7;

    float w2r[CIN], w1p[CIN], w1c[CIN];
#pragma unroll
    for (int c = 0; c < CIN; ++c) {
        w2r[c] = W2g[o * CIN + c];
        w1p[c] = W1g[(o * CIN + c) * 2 + 0];
        w1c[c] = W1g[(o * CIN + c) * 2 + 1];
    }
    const float bias = b2[o] + b1[o];

    // cell role: (cr, cj)
    const int cr = tid >> 5;
    const int cj = tid & 31;
    float pc = 0.f;

    __syncthreads();

    for (int t = 0; t < WW; ++t) {
        // ---- boundary wait + load (lanes 0..31, wave 0) ----
        if (k > 0 && tid < BO && t > 0) {
            while (__hip_atomic_load(&flags[b * NCH + k - 1], __ATOMIC_ACQUIRE,
                                     __HIP_MEMORY_SCOPE_AGENT) < t) {
                __builtin_amdgcn_s_sleep(1);
            }
            phs[0][tid] = __hip_atomic_load(
                &hand[((b * NCH + (k - 1)) * WW + (t - 1)) * BO + tid],
                __ATOMIC_RELAXED, __HIP_MEMORY_SCOPE_AGENT);
        }
        // ---- stage x for this step: xbuf[r][c] = x[b,c,h0+r,t-h] or 0 ----
        {
            const int r = tid >> 5, c = tid & 31;
            const int hh = h0 + r;
            const int wp = t - hh;
            float v = 0.f;
            if (wp >= 0) v = x[((b * CIN + c) * HH + hh) * WW + wp];
            xbuf[r][c] = v;
        }
        __syncthreads();

        // ---- matmul: each thread does 4 rows for its o ----
#pragma unroll
        for (int rr = 0; rr < 4; ++rr) {
            const int r = half * 4 + rr;
            float acc = bias;
#pragma unroll
            for (int c = 0; c < CIN; ++c) {
                acc = fmaf(w2r[c], xbuf[r][c], acc);
                acc = fmaf(w1p[c], phs[r][c], acc);      // ph[h-1] (prev step)
                acc = fmaf(w1c[c], phs[r + 1][c], acc);  // ph[h]   (prev step)
            }
            gbuf[r][o] = acc;
        }
        __syncthreads();

        // ---- cell update ----
        {
            const float go = gbuf[cr][cj];
            const float gf = gbuf[cr][BO + cj];
            const float gi = gbuf[cr][2 * BO + cj];
            const float gg = gbuf[cr][3 * BO + cj];
            const float so = 1.f / (1.f + __expf(-go));
            const float sf = 1.f / (1.f + __expf(-gf));
            const float si = 1.f / (1.f + __expf(-gi));
            const float tg = 2.f / (1.f + __expf(-2.f * gg)) - 1.f;
            const float nc = sf * pc + si * tg;
            const float th = 2.f / (1.f + __expf(-2.f * nc)) - 1.f;
            const float nh = so * th;
            pc = nc;
            phs[cr + 1][cj] = nh;
            out[((b * BO + cj) * HH + (h0 + cr)) * WW + t] = nh;
            if (cr == RPC - 1 && k < NCH - 1) {
                __hip_atomic_store(&hand[((b * NCH + k) * WW + t) * BO + cj], nh,
                                   __ATOMIC_RELAXED, __HIP_MEMORY_SCOPE_AGENT);
            }
        }
        __syncthreads();

        // ---- release flag for consumer chunk ----
        if (tid == 0 && k < NCH - 1) {
            __hip_atomic_store(&flags[b * NCH + k], t + 1, __ATOMIC_RELEASE,
                               __HIP_MEMORY_SCOPE_AGENT);
        }
    }
}

extern "C" void kernel_launch(void* const* d_in, const int* in_sizes, int n_in,
                              void* d_out, int out_size, void* d_ws, size_t ws_size,
                              hipStream_t stream) {
    const float* x  = (const float*)d_in[0];
    const float* W2 = (const float*)d_in[1];
    const float* b2 = (const float*)d_in[2];
    const float* W1 = (const float*)d_in[3];
    const float* b1 = (const float*)d_in[4];
    float* out = (float*)d_out;

    int*   flags = (int*)d_ws;
    float* hand  = (float*)((char*)d_ws + 1024);

    // reset flags each launch (graph-replay safe; memset node is capturable)
    hipMemsetAsync(d_ws, 0, 1024, stream);

    dim3 grid(BATCH * NCH), block(256);
    hipLaunchKernelGGL(diag_lstm_scan, grid, block, 0, stream,
                       x, W2, b2, W1, b1, out, flags, hand);
}

// Round 3
// 401.331 us; speedup vs baseline: 4.0076x; 4.0076x over previous
//
#include <hip/hip_runtime.h>
#include <stdint.h>

#define BATCH 16
#define CIN   32
#define HH    128
#define WW    128
#define BO    32
#define OCH   128   // 4*BO
#define NCH   16    // h-chunks
#define RPC   8     // rows per chunk
#define DEPTH 64    // handoff ring depth (power of 2)

// ws layout: [0, 4096): progress counters (int per (b,k), memset 0 each launch)
//            [4096, 4096 + BATCH*NCH*DEPTH*BO*8): tagged handoff ring (qwords)

__global__ __launch_bounds__(256) void diag_lstm_scan(
    const float* __restrict__ x, const float* __restrict__ W2g,
    const float* __restrict__ b2, const float* __restrict__ W1g,
    const float* __restrict__ b1, float* __restrict__ out,
    int* __restrict__ progress, unsigned long long* __restrict__ hand)
{
    const int tid = threadIdx.x;
    const int blk = blockIdx.x;
    // XCD-affinity remap: chain (b, k=0..15) stays on one XCD (assumes XCD = blk % 8)
    const int b = (blk & 7) + ((blk >> 7) << 3);
    const int k = (blk >> 3) & (NCH - 1);
    const int h0 = k * RPC;

    __shared__ float phs[RPC + 1][BO];   // [0] = boundary row (prev chunk, prev step)
    __shared__ float xbuf[RPC][CIN];
    __shared__ float gbuf[RPC][OCH];

    for (int i = tid; i < (RPC + 1) * BO; i += 256) ((float*)phs)[i] = 0.f;

    // matmul role
    const int o    = tid & (OCH - 1);
    const int half = tid >> 7;

    float w2r[CIN], w1p[CIN], w1c[CIN];
#pragma unroll
    for (int c = 0; c < CIN; ++c) {
        w2r[c] = W2g[o * CIN + c];
        w1p[c] = W1g[(o * CIN + c) * 2 + 0];
        w1c[c] = W1g[(o * CIN + c) * 2 + 1];
    }
    const float bias = b2[o] + b1[o];

    // cell role
    const int cr = tid >> 5;
    const int cj = tid & 31;
    float pc = 0.f;
    float obuf0 = 0.f, obuf1 = 0.f, obuf2 = 0.f;
    float* outrow = out + ((size_t)(b * BO + cj) * HH + (h0 + cr)) * WW;

    // handoff pointers
    const unsigned long long* srcbase =
        hand + (size_t)((b * NCH + (k - 1)) * DEPTH) * BO + tid;   // lane = tid (<32)
    unsigned long long* dstbase =
        hand + (size_t)((b * NCH + k) * DEPTH) * BO + cj;
    int* myprog   = progress + (b * NCH + k);
    int* consprog = progress + (b * NCH + k + 1);

    unsigned long long pre = 0ull;   // prefetched boundary qword (wave0 lanes<32)

    __syncthreads();

    for (int t = 0; t < WW; ++t) {
        // ---- phase 1: stage x, resolve boundary, prefetch next boundary ----
        {
            const int r = tid >> 5, c = tid & 31;
            const int wp = t - (h0 + r);
            xbuf[r][c] = (wp >= 0) ? x[((size_t)(b * CIN + c) * HH + (h0 + r)) * WW + wp] : 0.f;
        }
        if (k > 0 && tid < BO) {
            if (t > 0) {
                // producer's step t-1 value carries tag t, lives at slot (t-1)&63
                unsigned long long q = pre;
                while (__any((unsigned)(q >> 32) != (unsigned)t)) {
                    q = __hip_atomic_load(&srcbase[(size_t)((t - 1) & (DEPTH - 1)) * BO],
                                          __ATOMIC_RELAXED, __HIP_MEMORY_SCOPE_AGENT);
                }
                phs[0][tid] = __uint_as_float((unsigned)q);
            }
            // prefetch slot t (consumed at step t+1, expecting tag t+1)
            pre = __hip_atomic_load(&srcbase[(size_t)(t & (DEPTH - 1)) * BO],
                                    __ATOMIC_RELAXED, __HIP_MEMORY_SCOPE_AGENT);
        }
        __syncthreads();

        // ---- phase 2: matmul (4 rows per thread, register weights) ----
#pragma unroll
        for (int rr = 0; rr < 4; ++rr) {
            const int r = half * 4 + rr;
            float acc = bias;
#pragma unroll
            for (int c = 0; c < CIN; ++c) {
                acc = fmaf(w2r[c], xbuf[r][c], acc);
                acc = fmaf(w1p[c], phs[r][c], acc);      // ph[h-1] (prev step)
                acc = fmaf(w1c[c], phs[r + 1][c], acc);  // ph[h]   (prev step)
            }
            gbuf[r][o] = acc;
        }
        __syncthreads();

        // ---- phase 3: cell update ----
        {
            // rare back-pressure: producer lead stays < DEPTH
            if (cr == RPC - 1 && k < NCH - 1 && (t & 15) == 0 && t >= 48) {
                while (__hip_atomic_load(consprog, __ATOMIC_RELAXED,
                                         __HIP_MEMORY_SCOPE_AGENT) < t - 47) { }
            }
            const float go = gbuf[cr][cj];
            const float gf = gbuf[cr][BO + cj];
            const float gi = gbuf[cr][2 * BO + cj];
            const float gg = gbuf[cr][3 * BO + cj];
            const float so = 1.f / (1.f + __expf(-go));
            const float sf = 1.f / (1.f + __expf(-gf));
            const float si = 1.f / (1.f + __expf(-gi));
            const float tg = 2.f / (1.f + __expf(-2.f * gg)) - 1.f;
            const float nc = sf * pc + si * tg;
            const float th = 2.f / (1.f + __expf(-2.f * nc)) - 1.f;
            const float nh = so * th;
            pc = nc;
            phs[cr + 1][cj] = nh;

            // register-buffered output: one float4 store per 4 steps
            const int ph4 = t & 3;
            if (ph4 == 0) obuf0 = nh;
            else if (ph4 == 1) obuf1 = nh;
            else if (ph4 == 2) obuf2 = nh;
            else {
                float4 v = make_float4(obuf0, obuf1, obuf2, nh);
                *reinterpret_cast<float4*>(outrow + (t - 3)) = v;
            }

            if (cr == RPC - 1 && k < NCH - 1) {
                unsigned long long q = ((unsigned long long)(unsigned)(t + 1) << 32)
                                     | (unsigned long long)__float_as_uint(nh);
                __hip_atomic_store(&dstbase[(size_t)(t & (DEPTH - 1)) * BO], q,
                                   __ATOMIC_RELAXED, __HIP_MEMORY_SCOPE_AGENT);
            }
            if (tid == 0) {
                __hip_atomic_store(myprog, t + 1, __ATOMIC_RELAXED,
                                   __HIP_MEMORY_SCOPE_AGENT);
            }
        }
        __syncthreads();
    }
}

extern "C" void kernel_launch(void* const* d_in, const int* in_sizes, int n_in,
                              void* d_out, int out_size, void* d_ws, size_t ws_size,
                              hipStream_t stream) {
    const float* x  = (const float*)d_in[0];
    const float* W2 = (const float*)d_in[1];
    const float* b2 = (const float*)d_in[2];
    const float* W1 = (const float*)d_in[3];
    const float* b1 = (const float*)d_in[4];
    float* out = (float*)d_out;

    int* progress = (int*)d_ws;
    unsigned long long* hand = (unsigned long long*)((char*)d_ws + 4096);

    // reset progress + handoff tags each launch (stale tags from a previous
    // replay would alias valid tags -> must clear; ~2.1 MB)
    const size_t clr = 4096 + (size_t)BATCH * NCH * DEPTH * BO * 8;
    hipMemsetAsync(d_ws, 0, clr, stream);

    dim3 grid(BATCH * NCH), block(256);
    hipLaunchKernelGGL(diag_lstm_scan, grid, block, 0, stream,
                       x, W2, b2, W1, b1, out, progress, hand);
}

// Round 4
// 218.585 us; speedup vs baseline: 7.3580x; 1.8360x over previous
//
#include <hip/hip_runtime.h>
#include <stdint.h>

#define BATCH 16
#define CIN   32
#define HH    128
#define WW    128
#define BO    32
#define OCH   128   // 4*BO
#define NCH   16    // h-chunks (8 rows each)
#define NW    8     // waves per block == rows per chunk
#define DEPTH 64    // handoff ring depth (power of 2)

// ws: [0,4096) progress ints; [4096, +BATCH*NCH*DEPTH*BO*8) tagged ring

__global__ __launch_bounds__(512, 2) void diag_lstm_scan(
    const float* __restrict__ x, const float* __restrict__ W2g,
    const float* __restrict__ b2, const float* __restrict__ W1g,
    const float* __restrict__ b1, float* __restrict__ out,
    int* __restrict__ progress, unsigned long long* __restrict__ hand)
{
    const int tid = threadIdx.x;
    const int l   = tid & 63;           // lane
    const int w   = tid >> 6;           // wave id == local row
    const int blk = blockIdx.x;
    // XCD-affinity: chain (b, k=0..15) stays on one XCD (XCD = blk % 8 assumption)
    const int b = (blk & 7) + ((blk >> 7) << 3);
    const int k = (blk >> 3) & (NCH - 1);
    const int row = k * NW + w;         // global h row this wave owns

    __shared__ __attribute__((aligned(16))) float phs[2][NW + 1][BO]; // parity dbuf
    __shared__ __attribute__((aligned(16))) float xbuf[NW][CIN];      // wave-private
    __shared__ __attribute__((aligned(16))) float gbuf[NW][OCH];      // wave-private

    for (int i = tid; i < 2 * (NW + 1) * BO; i += 512) ((float*)phs)[i] = 0.f;

    // ---- per-lane weights: output channels o0=2l, o1=2l+1 (192 VGPRs) ----
    const int o0 = 2 * l, o1 = 2 * l + 1;
    float w2a[CIN], w2b[CIN], w1pa[CIN], w1ca[CIN], w1pb[CIN], w1cb[CIN];
#pragma unroll
    for (int c = 0; c < CIN; ++c) {
        w2a[c]  = W2g[o0 * CIN + c];
        w2b[c]  = W2g[o1 * CIN + c];
        w1pa[c] = W1g[(o0 * CIN + c) * 2 + 0];
        w1ca[c] = W1g[(o0 * CIN + c) * 2 + 1];
        w1pb[c] = W1g[(o1 * CIN + c) * 2 + 0];
        w1cb[c] = W1g[(o1 * CIN + c) * 2 + 1];
    }
    const float biasA = b2[o0] + b1[o0];
    const float biasB = b2[o1] + b1[o1];

    // cell role: lanes < 32, cell channel j = l
    const int j = l & 31;
    float pc = 0.f, ob0 = 0.f, ob1 = 0.f, ob2 = 0.f;
    float* outrow = out + ((size_t)(b * BO + j) * HH + row) * WW;

    const int kprev = (k > 0) ? k - 1 : 0;
    const unsigned long long* srcbase =
        hand + (size_t)((b * NCH + kprev) * DEPTH) * BO + j;
    unsigned long long* dstbase =
        hand + (size_t)((b * NCH + k) * DEPTH) * BO + j;
    int* myprog   = progress + (b * NCH + k);
    int* consprog = progress + (b * NCH + k) + 1;

    unsigned long long pre = 0ull;      // prefetched boundary qword (wave 0)

    __syncthreads();

    for (int t = 0; t < WW; ++t) {
        const int par = t & 1;          // gates read phs[par], cells write phs[par^1]

        // ---- stage x for own row (lanes<32, c=l) ----
        if (l < 32) {
            const int wp = t - row;
            float v = (wp >= 0) ? x[((size_t)(b * CIN + l) * HH + row) * WW + wp] : 0.f;
            xbuf[w][l] = v;
        }
        // ---- boundary poll (wave 0 only; value tagged t lives at slot (t-1)&63) ----
        if (w == 0 && k > 0) {
            if (t > 0) {
                unsigned long long q = pre;
                while (__any((unsigned)(q >> 32) != (unsigned)t)) {
                    q = __hip_atomic_load(&srcbase[(size_t)((t - 1) & (DEPTH - 1)) * BO],
                                          __ATOMIC_RELAXED, __HIP_MEMORY_SCOPE_AGENT);
                }
                if (l < 32) phs[par][0][l] = __uint_as_float((unsigned)q);
            }
            pre = __hip_atomic_load(&srcbase[(size_t)(t & (DEPTH - 1)) * BO],
                                    __ATOMIC_RELAXED, __HIP_MEMORY_SCOPE_AGENT);
        }
        // ensure xbuf / phs[par][0] writes complete before same-wave reads
        asm volatile("s_waitcnt lgkmcnt(0)" ::: "memory");

        // ---- gates for row w: 2 channels/lane, float4 broadcast inputs ----
        float ga = biasA, gb = biasB;
        {
            const float4* xb4 = (const float4*)(&xbuf[w][0]);
            const float4* pv4 = (const float4*)(&phs[par][w][0]);      // h(row-1) prev
            const float4* qv4 = (const float4*)(&phs[par][w + 1][0]);  // h(row)   prev
#pragma unroll
            for (int cc = 0; cc < CIN / 4; ++cc) {
                const float4 xv = xb4[cc];
                const float4 pv = pv4[cc];
                const float4 qv = qv4[cc];
                const float* xs = (const float*)&xv;
                const float* ps = (const float*)&pv;
                const float* qs = (const float*)&qv;
#pragma unroll
                for (int ci = 0; ci < 4; ++ci) {
                    const int c = 4 * cc + ci;
                    ga = fmaf(w2a[c],  xs[ci], ga);
                    gb = fmaf(w2b[c],  xs[ci], gb);
                    ga = fmaf(w1pa[c], ps[ci], ga);
                    gb = fmaf(w1pb[c], ps[ci], gb);
                    ga = fmaf(w1ca[c], qs[ci], ga);
                    gb = fmaf(w1cb[c], qs[ci], gb);
                }
            }
        }
        *(float2*)&gbuf[w][o0] = make_float2(ga, gb);
        asm volatile("s_waitcnt lgkmcnt(0)" ::: "memory");

        // ---- cell update for row w (lanes < 32), wave-private ----
        if (l < 32) {
            // rare back-pressure: producer lead stays < DEPTH
            if (w == NW - 1 && k < NCH - 1 && (t & 15) == 0 && t >= 48) {
                while (__hip_atomic_load(consprog, __ATOMIC_RELAXED,
                                         __HIP_MEMORY_SCOPE_AGENT) < t - 47) { }
            }
            const float go = gbuf[w][l];
            const float gf = gbuf[w][32 + l];
            const float gi = gbuf[w][64 + l];
            const float gg = gbuf[w][96 + l];
            const float so = 1.f / (1.f + __expf(-go));
            const float sf = 1.f / (1.f + __expf(-gf));
            const float si = 1.f / (1.f + __expf(-gi));
            const float tg = 2.f / (1.f + __expf(-2.f * gg)) - 1.f;
            const float nc = sf * pc + si * tg;
            const float th = 2.f / (1.f + __expf(-2.f * nc)) - 1.f;
            const float nh = so * th;
            pc = nc;
            phs[par ^ 1][w + 1][l] = nh;

            // buffered output: one float4 per 4 steps
            const int ph4 = t & 3;
            if (ph4 == 0) ob0 = nh;
            else if (ph4 == 1) ob1 = nh;
            else if (ph4 == 2) ob2 = nh;
            else *(float4*)(outrow + (t - 3)) = make_float4(ob0, ob1, ob2, nh);

            // early handoff (wave 7): tag t+1 into slot t&63
            if (w == NW - 1 && k < NCH - 1) {
                unsigned long long q = ((unsigned long long)(unsigned)(t + 1) << 32)
                                     | (unsigned long long)__float_as_uint(nh);
                __hip_atomic_store(&dstbase[(size_t)(t & (DEPTH - 1)) * BO], q,
                                   __ATOMIC_RELAXED, __HIP_MEMORY_SCOPE_AGENT);
            }
            if (w == 0 && l == 0) {
                __hip_atomic_store(myprog, t + 1, __ATOMIC_RELAXED,
                                   __HIP_MEMORY_SCOPE_AGENT);
            }
        }
        __syncthreads();   // publish phs[par^1] to neighbor waves
    }
}

extern "C" void kernel_launch(void* const* d_in, const int* in_sizes, int n_in,
                              void* d_out, int out_size, void* d_ws, size_t ws_size,
                              hipStream_t stream) {
    const float* x  = (const float*)d_in[0];
    const float* W2 = (const float*)d_in[1];
    const float* b2 = (const float*)d_in[2];
    const float* W1 = (const float*)d_in[3];
    const float* b1 = (const float*)d_in[4];
    float* out = (float*)d_out;

    int* progress = (int*)d_ws;
    unsigned long long* hand = (unsigned long long*)((char*)d_ws + 4096);

    // clear progress + ring tags (stale tags alias valid ones across replays)
    const size_t clr = 4096 + (size_t)BATCH * NCH * DEPTH * BO * 8;
    hipMemsetAsync(d_ws, 0, clr, stream);

    dim3 grid(BATCH * NCH), block(512);
    hipLaunchKernelGGL(diag_lstm_scan, grid, block, 0, stream,
                       x, W2, b2, W1, b1, out, progress, hand);
}